// Round 10
// baseline (793.713 us; speedup 1.0000x reference)
//
#include <hip/hip_runtime.h>

#define S_LEN  1024
#define H_DIM  4096
#define NHEAD  32
#define HEAD_D 128
#define RANK   16
#define KE3    4160   // QKV extended K: 4096 + 3*16 + 16 pad (130 * 32)
#define KEO    4128   // O-proj extended K: 4096 + 16 + 16 pad (129 * 32)
#define TOTP   ((long)NHEAD * S_LEN * S_LEN)

typedef __bf16 bf16x8 __attribute__((ext_vector_type(8)));
typedef float  f32x4  __attribute__((ext_vector_type(4)));
typedef unsigned short ushort8v __attribute__((ext_vector_type(8)));

#define GLOAD_LDS16(g, l) __builtin_amdgcn_global_load_lds( \
    (const __attribute__((address_space(1))) unsigned int*)(g), \
    (__attribute__((address_space(3))) unsigned int*)(l), 16, 0, 0)

__device__ const float NF4_TAB[16] = {
    -1.0f, -0.6961928009986877f, -0.5250730514526367f, -0.39491748809814453f,
    -0.28444138169288635f, -0.18477343022823334f, -0.09105003625154495f, 0.0f,
    0.07958029955625534f, 0.16093020141124725f, 0.24611230194568634f,
    0.33791524171829224f, 0.4407098591327667f, 0.5626170039176941f,
    0.7229568362236023f, 1.0f};

__device__ __forceinline__ unsigned short f2bf(float f) {
    unsigned int u = __builtin_bit_cast(unsigned int, f);
    u = (u + 0x7FFFu + ((u >> 16) & 1u)) >> 16;   // RNE
    return (unsigned short)u;
}

__device__ __forceinline__ float bf2f(unsigned short s) {
    return __builtin_bit_cast(float, (unsigned int)s << 16);
}

// ---------------- plain dequant NF4 -> bf16, strided output row ----------------
__device__ __forceinline__ void dequant_body(
    const int* __restrict__ codes, const float* __restrict__ absmax,
    unsigned short* __restrict__ out, long i, int ostride) {
    int4 c0 = *(const int4*)(codes + i);
    int4 c1 = *(const int4*)(codes + i + 4);
    float am = absmax[i >> 6];
    long orow = i >> 12;                 // H_DIM = 4096
    int  col  = (int)(i & 4095);
    ushort8v r;
    r[0] = f2bf(NF4_TAB[c0.x] * am);
    r[1] = f2bf(NF4_TAB[c0.y] * am);
    r[2] = f2bf(NF4_TAB[c0.z] * am);
    r[3] = f2bf(NF4_TAB[c0.w] * am);
    r[4] = f2bf(NF4_TAB[c1.x] * am);
    r[5] = f2bf(NF4_TAB[c1.y] * am);
    r[6] = f2bf(NF4_TAB[c1.z] * am);
    r[7] = f2bf(NF4_TAB[c1.w] * am);
    *(ushort8v*)(out + orow * ostride + col) = r;
}

// ---------------- prep: 4 dequants + lbT pads + bias gather + hist zero ----------
__global__ __launch_bounds__(256) void prep_weights(
    const int* __restrict__ c0, const int* __restrict__ c1,
    const int* __restrict__ c2, const int* __restrict__ c3,
    const float* __restrict__ a0, const float* __restrict__ a1,
    const float* __restrict__ a2, const float* __restrict__ a3,
    const float* __restrict__ lb0, const float* __restrict__ lb1,
    const float* __restrict__ lb2, const float* __restrict__ lb3,
    const float* __restrict__ b0, const float* __restrict__ b1,
    const float* __restrict__ b2,
    unsigned short* __restrict__ wqkv, unsigned short* __restrict__ wo,
    float* __restrict__ bias3, unsigned int* __restrict__ hist, long n) {
    int p = blockIdx.y;
    long bx = blockIdx.x;
    int tid = threadIdx.x;
    if (bx < 8192) {
        const int* codes = (p == 0) ? c0 : (p == 1) ? c1 : (p == 2) ? c2 : c3;
        const float* am  = (p == 0) ? a0 : (p == 1) ? a1 : (p == 2) ? a2 : a3;
        long i = (bx * 256 + tid) * 8;
        if (i >= n) return;
        if (p < 3) dequant_body(codes, am, wqkv + (size_t)p * H_DIM * KE3, i, KE3);
        else       dequant_body(codes, am, wo, i, KEO);
        return;
    }
    if (p < 3) {
        long g = (bx - 8192) * 256 + tid;
        int row = (int)(g >> 6), c = (int)(g & 63);
        const float* lb = (p == 0) ? lb0 : (p == 1) ? lb1 : lb2;
        unsigned int r = (unsigned int)(c - 16 * p);
        float v = (r < 16u) ? lb[r * H_DIM + row] : 0.f;
        wqkv[(size_t)p * H_DIM * KE3 + (long)row * KE3 + 4096 + c] = f2bf(v);
        if (g < H_DIM) {
            const float* bp = (p == 0) ? b0 : (p == 1) ? b1 : b2;
            bias3[(size_t)p * H_DIM + g] = bp[g];
        }
        return;
    }
    if (bx < 8704) {
        long g = (bx - 8192) * 256 + tid;
        if (g >= (long)H_DIM * 32) return;
        int row = (int)(g >> 5), c = (int)(g & 31);
        float v = (c < 16) ? lb3[c * H_DIM + row] : 0.f;
        wo[(long)row * KEO + 4096 + c] = f2bf(v);
        return;
    }
    if (bx < 9088) {
        long g = (bx - 8704) * 256 + tid;
        if (g < 6 * 16384) hist[g] = 0u;
    }
}

// ---------------- fused x cast (fp32->bf16, stride KE3) + 3x lora_a ------------
__global__ __launch_bounds__(256) void cast_lora(
    const float* __restrict__ x, const float* __restrict__ la0,
    const float* __restrict__ la1, const float* __restrict__ la2,
    unsigned short* __restrict__ xb_ext) {
    __shared__ float xs[4096];
    int m = blockIdx.x, tid = threadIdx.x;
    const float* xr = x + (long)m * H_DIM;
    int c = tid * 16;
    float4 f0 = *(const float4*)(xr + c);
    float4 f1 = *(const float4*)(xr + c + 4);
    float4 f2 = *(const float4*)(xr + c + 8);
    float4 f3 = *(const float4*)(xr + c + 12);
    *(float4*)(xs + c)      = f0;
    *(float4*)(xs + c + 4)  = f1;
    *(float4*)(xs + c + 8)  = f2;
    *(float4*)(xs + c + 12) = f3;
    ushort8v r0, r1;
    r0[0] = f2bf(f0.x); r0[1] = f2bf(f0.y); r0[2] = f2bf(f0.z); r0[3] = f2bf(f0.w);
    r0[4] = f2bf(f1.x); r0[5] = f2bf(f1.y); r0[6] = f2bf(f1.z); r0[7] = f2bf(f1.w);
    r1[0] = f2bf(f2.x); r1[1] = f2bf(f2.y); r1[2] = f2bf(f2.z); r1[3] = f2bf(f2.w);
    r1[4] = f2bf(f3.x); r1[5] = f2bf(f3.y); r1[6] = f2bf(f3.z); r1[7] = f2bf(f3.w);
    unsigned short* orow = xb_ext + (long)m * KE3 + c;
    *(ushort8v*)orow = r0;
    *(ushort8v*)(orow + 8) = r1;
    __syncthreads();
    int w = tid >> 6, lane = tid & 63;
    if (w < 3) {
        const float* la = (w == 0) ? la0 : (w == 1) ? la1 : la2;
        float s[16];
#pragma unroll
        for (int r = 0; r < 16; ++r) s[r] = 0.f;
        for (int k = lane; k < H_DIM; k += 64) {
            float xv = xs[k];
            const float4* lr = (const float4*)(la + (long)k * RANK);
            float4 q0 = lr[0], q1 = lr[1], q2 = lr[2], q3 = lr[3];
            s[0] += xv * q0.x;  s[1] += xv * q0.y;  s[2] += xv * q0.z;  s[3] += xv * q0.w;
            s[4] += xv * q1.x;  s[5] += xv * q1.y;  s[6] += xv * q1.z;  s[7] += xv * q1.w;
            s[8] += xv * q2.x;  s[9] += xv * q2.y;  s[10] += xv * q2.z; s[11] += xv * q2.w;
            s[12] += xv * q3.x; s[13] += xv * q3.y; s[14] += xv * q3.z; s[15] += xv * q3.w;
        }
        for (int off = 32; off; off >>= 1)
#pragma unroll
            for (int r = 0; r < 16; ++r) s[r] += __shfl_xor(s[r], off);
        if (lane == 0)
#pragma unroll
            for (int r = 0; r < 16; ++r)
                xb_ext[(long)m * KE3 + 4096 + 16 * w + r] = f2bf(s[r]);
    }
}

// xa_o = ob @ la_o (bf16 in) -> bf16 cols of ob_ext
__global__ __launch_bounds__(256) void lora_ao_kernel(
    unsigned short* __restrict__ ob_ext, const float* __restrict__ la) {
    int m = blockIdx.x;
    const unsigned short* xr = ob_ext + (long)m * KEO;
    int tid = threadIdx.x, lane = tid & 63, wid = tid >> 6;
    float s[4] = {0.f, 0.f, 0.f, 0.f};
    for (int k = lane; k < H_DIM; k += 64) {
        float xv = bf2f(xr[k]);
        const float* lr = la + (long)k * RANK + wid * 4;
        s[0] += xv * lr[0]; s[1] += xv * lr[1];
        s[2] += xv * lr[2]; s[3] += xv * lr[3];
    }
    for (int off = 32; off; off >>= 1)
        for (int r = 0; r < 4; ++r) s[r] += __shfl_down(s[r], off);
    if (lane == 0)
        for (int r = 0; r < 4; ++r)
            ob_ext[(long)m * KEO + 4096 + wid * 4 + r] = f2bf(s[r]);
}

// ---------------- bf16 NT GEMM: C[m][n] = alpha*sum_k A[m][k]*B[n][k] (+bias[n]) ------
// L2-locality swizzle: bm = blockIdx.x (consecutive ids share bm -> one A strip per XCD).
// mode 0: plain batched (z). mode 1: causal triangular grid (x<36: tri idx, z=head;
//         x in [36,40): v->vT transpose region using tsrc/tdst).
// mode 2: batched + K limited to bm+128 (causal PV). mode 3: split-K2 (z half -> Cv/Cv2).
__global__ __launch_bounds__(256) void gemm_nt(
    const unsigned short* __restrict__ A, const unsigned short* __restrict__ B,
    void* __restrict__ Cv, void* __restrict__ Cv2, const float* __restrict__ bias,
    int K, int lda, int ldb, int ldc,
    long strideA, long strideB, long strideC, float alpha, int mode, int obf,
    const unsigned short* __restrict__ tsrc, unsigned short* __restrict__ tdst) {
    __shared__ unsigned short As[128][32];   // UNPADDED: global_load_lds lane-order
    __shared__ unsigned short Bs[128][32];
    const int tid = threadIdx.x;
    int bm, bn;
    int k0s = 0, k0e = K;
    if (mode == 1) {
        int i = blockIdx.x;
        if (i >= 36) {
            // transpose region: 128 blocks, 32 tiles of 32x32 each, padded LDS
            unsigned short (*tl)[33] = (unsigned short(*)[33])&As[0][0];
            int tb = (i - 36) + 4 * blockIdx.z;
            int tx = tid & 31, ty = tid >> 5;           // 8 rows per pass
            for (int tile = tb; tile < 4096; tile += 128) {
                int tc = tile & 127, ts = tile >> 7;
                int c0 = tc * 32, s0 = ts * 32;
                for (int j = 0; j < 32; j += 8)
                    tl[ty + j][tx] = tsrc[(long)(s0 + ty + j) * H_DIM + c0 + tx];
                __syncthreads();
                for (int j = 0; j < 32; j += 8)
                    tdst[(long)(c0 + ty + j) * S_LEN + s0 + tx] = tl[tx][ty + j];
                __syncthreads();
            }
            return;
        }
        int tm = (int)((sqrtf(8.f * i + 1.f) - 1.f) * 0.5f);
        if ((tm + 1) * (tm + 2) / 2 <= i) tm++;
        if (tm * (tm + 1) / 2 > i) tm--;
        int tn = i - tm * (tm + 1) / 2;
        bm = tm * 128; bn = tn * 128;
    } else {
        bm = blockIdx.x * 128; bn = blockIdx.y * 128;   // swizzled: x=M, y=N
        if (mode == 2) { int kl = bm + 128; if (kl < k0e) k0e = kl; }
    }
    const unsigned short* Ab = A;
    const unsigned short* Bb = B;
    long coff = 0;
    void* Cuse = Cv;
    if (mode == 3) {
        int Kh = (K / 2) & ~31;
        k0s = blockIdx.z ? Kh : 0;
        k0e = blockIdx.z ? K : Kh;
        Cuse = blockIdx.z ? Cv2 : Cv;
    } else {
        Ab += (long)blockIdx.z * strideA;
        Bb += (long)blockIdx.z * strideB;
        coff = (long)blockIdx.z * strideC;
    }
    const int lane = tid & 63, wid = tid >> 6;
    const int wm = (wid >> 1) * 64, wn = (wid & 1) * 64;
    const int sr = wid * 16 + (lane >> 2);
    const int sc = (lane & 3) * 8;
    const unsigned short* gA0 = Ab + (long)(bm + sr) * lda + sc;
    const unsigned short* gA1 = gA0 + (long)64 * lda;
    const unsigned short* gB0 = Bb + (long)(bn + sr) * ldb + sc;
    const unsigned short* gB1 = gB0 + (long)64 * ldb;
    unsigned short* lA0 = &As[wid * 16][0];
    unsigned short* lA1 = &As[64 + wid * 16][0];
    unsigned short* lB0 = &Bs[wid * 16][0];
    unsigned short* lB1 = &Bs[64 + wid * 16][0];
    f32x4 acc[4][4] = {};
    const int kq = (lane >> 4) * 8;
    const int rr = lane & 15;
    for (int k0 = k0s; k0 < k0e; k0 += 32) {
        GLOAD_LDS16(gA0 + k0, lA0);
        GLOAD_LDS16(gA1 + k0, lA1);
        GLOAD_LDS16(gB0 + k0, lB0);
        GLOAD_LDS16(gB1 + k0, lB1);
        __syncthreads();
        bf16x8 af[4], bfr[4];
        for (int i = 0; i < 4; ++i) {
            uint4 ta = *(const uint4*)&As[wm + i * 16 + rr][kq];
            uint4 tb = *(const uint4*)&Bs[wn + i * 16 + rr][kq];
            af[i]  = __builtin_bit_cast(bf16x8, ta);
            bfr[i] = __builtin_bit_cast(bf16x8, tb);
        }
        for (int i = 0; i < 4; ++i)
            for (int j = 0; j < 4; ++j)
                acc[i][j] = __builtin_amdgcn_mfma_f32_16x16x32_bf16(
                    af[i], bfr[j], acc[i][j], 0, 0, 0);
        __syncthreads();
    }
    const int cr = (lane >> 4) * 4;
    const int cc = lane & 15;
    float bv[4];
#pragma unroll
    for (int j = 0; j < 4; ++j)
        bv[j] = bias ? bias[(long)blockIdx.z * H_DIM + bn + wn + j * 16 + cc] : 0.f;
    if (obf) {
        unsigned short* Cb = (unsigned short*)Cuse + coff;
        for (int i = 0; i < 4; ++i)
            for (int j = 0; j < 4; ++j) {
                unsigned short* cp = Cb + (long)(bm + wm + i * 16 + cr) * ldc
                                        + (bn + wn + j * 16 + cc);
                for (int r = 0; r < 4; ++r)
                    cp[(long)r * ldc] = f2bf(acc[i][j][r] * alpha + bv[j]);
            }
    } else {
        float* Cb = (float*)Cuse + coff;
        for (int i = 0; i < 4; ++i)
            for (int j = 0; j < 4; ++j) {
                float* cp = Cb + (long)(bm + wm + i * 16 + cr) * ldc
                               + (bn + wn + j * 16 + cc);
                for (int r = 0; r < 4; ++r)
                    cp[(long)r * ldc] = acc[i][j][r] * alpha + bv[j];
            }
    }
}

// ---------------- causal softmax, bf16 in/out in-place, 2 balanced rows/block ----
__global__ __launch_bounds__(256) void softmax_causal(unsigned short* __restrict__ scores16) {
    int b = blockIdx.x;
    int h = b >> 9, pr = b & 511;
    int tid = threadIdx.x, lane = tid & 63, wid = tid >> 6;
    __shared__ float red[4], red2[4];
    for (int half = 0; half < 2; ++half) {
        int i = half ? (S_LEN - 1 - pr) : pr;
        unsigned short* row = scores16 + ((long)h * S_LEN + i) * S_LEN;
        int L = i + 1;
        float v[4];
        float mx = -1e30f;
        for (int t = 0; t < 4; ++t) {
            int j = tid + (t << 8);
            v[t] = (j < L) ? bf2f(row[j]) : -1e30f;
            mx = fmaxf(mx, v[t]);
        }
        for (int off = 32; off; off >>= 1) mx = fmaxf(mx, __shfl_xor(mx, off));
        if (lane == 0) red[wid] = mx;
        __syncthreads();
        mx = fmaxf(fmaxf(red[0], red[1]), fmaxf(red[2], red[3]));
        float e[4], sum = 0.f;
        for (int t = 0; t < 4; ++t) {
            int j = tid + (t << 8);
            e[t] = (j < L) ? __expf(v[t] - mx) : 0.f;
            sum += e[t];
        }
        for (int off = 32; off; off >>= 1) sum += __shfl_xor(sum, off);
        if (lane == 0) red2[wid] = sum;
        __syncthreads();
        sum = red2[0] + red2[1] + red2[2] + red2[3];
        float inv = 1.f / sum;
        for (int t = 0; t < 4; ++t) {
            int j = tid + (t << 8);
            row[j] = f2bf(e[t] * inv);
        }
        __syncthreads();
    }
}

// ---------------- mega histogram: 6 tensors, flat weighted grid (1536 blocks) ----
// [0,256) x fp32 | [256,384) q | [384,512) k | [512,640) v | [640,768) o | [768,1536) P
__global__ __launch_bounds__(256, 2) void hist6(
    const float* __restrict__ x, const unsigned short* __restrict__ qkv,
    const unsigned short* __restrict__ ob, const unsigned short* __restrict__ P,
    unsigned int* __restrict__ hist) {
    __shared__ unsigned int lh[16384];
    const long SH = (long)S_LEN * H_DIM;
    int t = threadIdx.x;
    int b = blockIdx.x;
    int ten, b0, nblk;
    if (b < 256)      { ten = 0; b0 = 0;   nblk = 256; }
    else if (b < 384) { ten = 1; b0 = 256; nblk = 128; }
    else if (b < 512) { ten = 2; b0 = 384; nblk = 128; }
    else if (b < 640) { ten = 3; b0 = 512; nblk = 128; }
    else if (b < 768) { ten = 4; b0 = 640; nblk = 128; }
    else              { ten = 5; b0 = 768; nblk = 768; }
    unsigned int* gh = hist + (long)ten * 16384;
    for (int k = t; k < 16384; k += 256) lh[k] = 0u;
    __syncthreads();
    long i = (long)(b - b0) * 256 + t;
    long stride = (long)nblk * 256;
    if (ten == 0) {
        for (; i < SH / 4; i += stride) {
            float4 v = *(const float4*)(x + i * 4);
            unsigned int u0 = (__builtin_bit_cast(unsigned int, v.x) & 0x7FFFFFFFu) >> 16;
            unsigned int u1 = (__builtin_bit_cast(unsigned int, v.y) & 0x7FFFFFFFu) >> 16;
            unsigned int u2 = (__builtin_bit_cast(unsigned int, v.z) & 0x7FFFFFFFu) >> 16;
            unsigned int u3 = (__builtin_bit_cast(unsigned int, v.w) & 0x7FFFFFFFu) >> 16;
            atomicAdd(&lh[u0 < 16384u ? u0 : 16383u], 1u);
            atomicAdd(&lh[u1 < 16384u ? u1 : 16383u], 1u);
            atomicAdd(&lh[u2 < 16384u ? u2 : 16383u], 1u);
            atomicAdd(&lh[u3 < 16384u ? u3 : 16383u], 1u);
        }
    } else if (ten <= 3) {
        const unsigned short* src = qkv + (size_t)(ten - 1) * SH;
        for (; i < SH / 8; i += stride) {
            ushort8v v = ((const ushort8v*)src)[i];
#pragma unroll
            for (int j = 0; j < 8; ++j) {
                unsigned int u = v[j] & 0x7FFFu;
                atomicAdd(&lh[u < 16384u ? u : 16383u], 1u);
            }
        }
    } else if (ten == 4) {
        for (; i < SH / 8; i += stride) {
            long off = (i >> 9) * KEO + ((i & 511) << 3);
            ushort8v v = *(const ushort8v*)(ob + off);
#pragma unroll
            for (int j = 0; j < 8; ++j) {
                unsigned int u = v[j] & 0x7FFFu;
                atomicAdd(&lh[u < 16384u ? u : 16383u], 1u);
            }
        }
    } else {
        unsigned int zc = 0;
        for (; i < TOTP / 8; i += stride) {
            ushort8v v = ((const ushort8v*)P)[i];
#pragma unroll
            for (int j = 0; j < 8; ++j) {
                unsigned int bb = v[j];
                if (bb == 0) zc++;
                else atomicAdd(&lh[bb < 16384u ? bb : 16383u], 1u);
            }
        }
        if (zc) atomicAdd(&lh[0], zc);
    }
    __syncthreads();
    for (int k = t; k < 16384; k += 256) {
        unsigned int c = lh[k];
        if (c) atomicAdd(&gh[k], c);
    }
}

// ---------------- finish: combine split-K + bias (b<4096) | scan6 (b>=4096) ------
__global__ __launch_bounds__(256) void finish_kernel(
    float* __restrict__ out, const float* __restrict__ part,
    const float* __restrict__ bias, const unsigned int* __restrict__ hist,
    float* __restrict__ out_kth) {
    int b = blockIdx.x;
    int t = threadIdx.x;
    if (b < 4096) {
        long idx = ((long)b * 256 + t) * 4;
        int n = (int)(idx & 4095);
        float4 o = *(float4*)(out + idx);
        float4 p = *(const float4*)(part + idx);
        float4 bb = *(const float4*)(bias + n);
        o.x += p.x + bb.x; o.y += p.y + bb.y; o.z += p.z + bb.z; o.w += p.w + bb.w;
        *(float4*)(out + idx) = o;
        return;
    }
    int ten = b - 4096;
    const unsigned int* h = hist + (long)ten * 16384;
    __shared__ unsigned int partl[256];
    unsigned int s = 0;
    for (int bb = 0; bb < 64; ++bb) s += h[t * 64 + bb];
    partl[t] = s;
    __syncthreads();
    if (t == 0) {
        long k = (ten == 5) ? TOTP / 2 : (long)S_LEN * H_DIM / 2;
        long c = 0;
        int ch = 0;
        for (; ch < 256; ++ch) {
            if (c + (long)partl[ch] >= k) break;
            c += partl[ch];
        }
        int bin = ch * 64;
        for (;; ++bin) {
            unsigned int hv = h[bin];
            if (c + (long)hv >= k) break;
            c += hv;
        }
        int slot = (ten == 4) ? 5 : (ten == 5) ? 4 : ten;
        out_kth[slot] = __builtin_bit_cast(float, (unsigned int)bin << 16);
    }
}

// ==================================================================
extern "C" void kernel_launch(void* const* d_in, const int* in_sizes, int n_in,
                              void* d_out, int out_size, void* d_ws, size_t ws_size,
                              hipStream_t stream) {
    (void)in_sizes; (void)n_in; (void)out_size; (void)ws_size;
    const float* x = (const float*)d_in[0];
    const int*   wcodes[4] = {(const int*)d_in[1], (const int*)d_in[6],
                              (const int*)d_in[11], (const int*)d_in[16]};
    const float* wabs[4]   = {(const float*)d_in[2], (const float*)d_in[7],
                              (const float*)d_in[12], (const float*)d_in[17]};
    const float* bias[4]   = {(const float*)d_in[3], (const float*)d_in[8],
                              (const float*)d_in[13], (const float*)d_in[18]};
    const float* lA[4]     = {(const float*)d_in[4], (const float*)d_in[9],
                              (const float*)d_in[14], (const float*)d_in[19]};
    const float* lB[4]     = {(const float*)d_in[5], (const float*)d_in[10],
                              (const float*)d_in[15], (const float*)d_in[20]};

    char* wp = (char*)d_ws;
    auto alloc = [&](size_t bytes) {
        char* p = wp; wp += (bytes + 255) & ~(size_t)255; return p;
    };
    const size_t SH  = (size_t)S_LEN * H_DIM;       // 4,194,304
    const long   nW  = (long)H_DIM * H_DIM;
    unsigned short* xb_ext = (unsigned short*)alloc((size_t)S_LEN * KE3 * 2);
    unsigned short* qkvb   = (unsigned short*)alloc(3 * SH * 2);  // q,k,v bf16
    unsigned short* vT     = (unsigned short*)alloc(SH * 2);
    unsigned short* ob_ext = (unsigned short*)alloc((size_t)S_LEN * KEO * 2);
    unsigned short* Wd_ext = (unsigned short*)alloc((size_t)H_DIM * KEO * 2);
    float*        opart  = (float*)alloc(SH * 4);
    float*        bias3  = (float*)alloc(3 * H_DIM * 4);
    unsigned int* hist   = (unsigned int*)alloc(6 * 16384 * 4);
    // scores16 (bf16 P, 67 MB) aliases the region that first holds Wqkv_ext (102 MB)
    char* bigbuf = alloc((size_t)3 * H_DIM * KE3 * 2);
    unsigned short* Wqkv_ext = (unsigned short*)bigbuf;
    unsigned short* scores16 = (unsigned short*)bigbuf;

    float* out_final = (float*)d_out;
    float* out_kth   = out_final + SH;

    unsigned short* qb = qkvb;
    unsigned short* kb = qkvb + SH;
    unsigned short* vb = qkvb + 2 * SH;

    // 1) prep: dequants + pads + bias + hist zero (pure streaming)
    prep_weights<<<dim3(9216, 4), 256, 0, stream>>>(
        wcodes[0], wcodes[1], wcodes[2], wcodes[3],
        wabs[0], wabs[1], wabs[2], wabs[3],
        lB[0], lB[1], lB[2], lB[3],
        bias[0], bias[1], bias[2],
        Wqkv_ext, Wd_ext, bias3, hist, nW);

    // 2) x cast + xa columns (1 row per block, 1024 blocks)
    cast_lora<<<S_LEN, 256, 0, stream>>>(x, lA[0], lA[1], lA[2], xb_ext);

    // 3) QKV: ONE z=3 batched GEMM over K=4160, L2-swizzled grid (M-tiles on x)
    gemm_nt<<<dim3(8, 32, 3), 256, 0, stream>>>(
        xb_ext, Wqkv_ext, qkvb, nullptr, bias3, KE3, KE3, KE3, H_DIM,
        0, (long)H_DIM * KE3, (long)SH, 1.0f, 0, 1, nullptr, nullptr);

    // 4) scores16 = q.kT / sqrt(128) bf16 (36 tri tiles/head) + v->vT (x>=36 region)
    gemm_nt<<<dim3(40, 1, NHEAD), 256, 0, stream>>>(
        qb, kb, scores16, nullptr, nullptr, HEAD_D, H_DIM, H_DIM, S_LEN,
        128, 128, (long)S_LEN * S_LEN, 0.08838834764831845f, 1, 1, vb, vT);

    // 5) softmax in-place bf16, 2 balanced rows per block
    softmax_causal<<<NHEAD * S_LEN / 2, 256, 0, stream>>>(scores16);

    // 6) o = P.v -> ob_ext (bf16, row stride KEO); mode 2 limits K to bm+128
    gemm_nt<<<dim3(8, 1, NHEAD), 256, 0, stream>>>(
        scores16, vT, ob_ext, nullptr, nullptr, S_LEN,
        S_LEN, S_LEN, KEO,
        (long)S_LEN * S_LEN, (long)HEAD_D * S_LEN, 128, 1.0f, 2, 1, nullptr, nullptr);

    // 7) xa_o columns
    lora_ao_kernel<<<S_LEN, 256, 0, stream>>>(ob_ext, lA[3]);

    // 8) O projection: split-K2 (z=2), L2-swizzled grid
    gemm_nt<<<dim3(8, 32, 2), 256, 0, stream>>>(
        ob_ext, Wd_ext, out_final, opart, nullptr, KEO, KEO, KEO, H_DIM,
        0, 0, 0, 1.0f, 3, 0, nullptr, nullptr);

    // 9) k-th selects: one 6-tensor histogram (hist zeroed in prep)
    hist6<<<1536, 256, 0, stream>>>(x, qkvb, ob_ext, scores16, hist);

    // 10) finish: combine split-K partials + bias, and scan the 6 histograms
    finish_kernel<<<4102, 256, 0, stream>>>(out_final, opart, bias[3], hist, out_kth);
}

// Round 11
// 774.179 us; speedup vs baseline: 1.0252x; 1.0252x over previous
//
#include <hip/hip_runtime.h>

#define S_LEN  1024
#define H_DIM  4096
#define NHEAD  32
#define HEAD_D 128
#define RANK   16
#define KE3    4160   // QKV extended K: 4096 + 3*16 + 16 pad (130 * 32)
#define KEO    4128   // O-proj extended K: 4096 + 16 + 16 pad (129 * 32)
#define TOTP   ((long)NHEAD * S_LEN * S_LEN)

typedef __bf16 bf16x8 __attribute__((ext_vector_type(8)));
typedef float  f32x4  __attribute__((ext_vector_type(4)));
typedef unsigned short ushort8v __attribute__((ext_vector_type(8)));

#define GLOAD_LDS16(g, l) __builtin_amdgcn_global_load_lds( \
    (const __attribute__((address_space(1))) unsigned int*)(g), \
    (__attribute__((address_space(3))) unsigned int*)(l), 16, 0, 0)

__device__ const float NF4_TAB[16] = {
    -1.0f, -0.6961928009986877f, -0.5250730514526367f, -0.39491748809814453f,
    -0.28444138169288635f, -0.18477343022823334f, -0.09105003625154495f, 0.0f,
    0.07958029955625534f, 0.16093020141124725f, 0.24611230194568634f,
    0.33791524171829224f, 0.4407098591327667f, 0.5626170039176941f,
    0.7229568362236023f, 1.0f};

__device__ __forceinline__ unsigned short f2bf(float f) {
    unsigned int u = __builtin_bit_cast(unsigned int, f);
    u = (u + 0x7FFFu + ((u >> 16) & 1u)) >> 16;   // RNE
    return (unsigned short)u;
}

__device__ __forceinline__ float bf2f(unsigned short s) {
    return __builtin_bit_cast(float, (unsigned int)s << 16);
}

// ---------------- plain dequant NF4 -> bf16, strided output row ----------------
__device__ __forceinline__ void dequant_body(
    const int* __restrict__ codes, const float* __restrict__ absmax,
    unsigned short* __restrict__ out, long i, int ostride) {
    int4 c0 = *(const int4*)(codes + i);
    int4 c1 = *(const int4*)(codes + i + 4);
    float am = absmax[i >> 6];
    long orow = i >> 12;                 // H_DIM = 4096
    int  col  = (int)(i & 4095);
    ushort8v r;
    r[0] = f2bf(NF4_TAB[c0.x] * am);
    r[1] = f2bf(NF4_TAB[c0.y] * am);
    r[2] = f2bf(NF4_TAB[c0.z] * am);
    r[3] = f2bf(NF4_TAB[c0.w] * am);
    r[4] = f2bf(NF4_TAB[c1.x] * am);
    r[5] = f2bf(NF4_TAB[c1.y] * am);
    r[6] = f2bf(NF4_TAB[c1.z] * am);
    r[7] = f2bf(NF4_TAB[c1.w] * am);
    *(ushort8v*)(out + orow * ostride + col) = r;
}

// -------- prep: 4 dequants + lbT pads + bias + hist zero + x cast/lora --------
// grid dim3(10240, 4):
//  bx<8192               : dequant main region (all p)
//  p<3,  bx in [8192,9216): lbT/zero pad cols + bias gather
//  p==3, bx in [8192,8704): wo pad cols
//  p==3, bx in [8704,9088): zero hist buffer (6*16384 uints)
//  p==0, bx in [9216,10240): x cast + 3x lora_a (1 row per block) — EARLY ids,
//                            overlaps the dequant stream (round-8 tail lesson)
__global__ __launch_bounds__(256) void prep_weights(
    const int* __restrict__ c0, const int* __restrict__ c1,
    const int* __restrict__ c2, const int* __restrict__ c3,
    const float* __restrict__ a0, const float* __restrict__ a1,
    const float* __restrict__ a2, const float* __restrict__ a3,
    const float* __restrict__ lb0, const float* __restrict__ lb1,
    const float* __restrict__ lb2, const float* __restrict__ lb3,
    const float* __restrict__ b0, const float* __restrict__ b1,
    const float* __restrict__ b2,
    const float* __restrict__ x, const float* __restrict__ la0,
    const float* __restrict__ la1, const float* __restrict__ la2,
    unsigned short* __restrict__ wqkv, unsigned short* __restrict__ wo,
    float* __restrict__ bias3, unsigned short* __restrict__ xb_ext,
    unsigned int* __restrict__ hist, long n) {
    __shared__ float xs[4096];
    int p = blockIdx.y;
    long bx = blockIdx.x;
    int tid = threadIdx.x;
    if (bx < 8192) {
        const int* codes = (p == 0) ? c0 : (p == 1) ? c1 : (p == 2) ? c2 : c3;
        const float* am  = (p == 0) ? a0 : (p == 1) ? a1 : (p == 2) ? a2 : a3;
        long i = (bx * 256 + tid) * 8;
        if (i >= n) return;
        if (p < 3) dequant_body(codes, am, wqkv + (size_t)p * H_DIM * KE3, i, KE3);
        else       dequant_body(codes, am, wo, i, KEO);
        return;
    }
    if (bx < 9216) {
        if (p < 3) {
            long g = (bx - 8192) * 256 + tid;
            int row = (int)(g >> 6), c = (int)(g & 63);
            const float* lb = (p == 0) ? lb0 : (p == 1) ? lb1 : lb2;
            unsigned int r = (unsigned int)(c - 16 * p);
            float v = (r < 16u) ? lb[r * H_DIM + row] : 0.f;
            wqkv[(size_t)p * H_DIM * KE3 + (long)row * KE3 + 4096 + c] = f2bf(v);
            if (g < H_DIM) {
                const float* bp = (p == 0) ? b0 : (p == 1) ? b1 : b2;
                bias3[(size_t)p * H_DIM + g] = bp[g];
            }
            return;
        }
        if (bx < 8704) {
            long g = (bx - 8192) * 256 + tid;
            if (g >= (long)H_DIM * 32) return;
            int row = (int)(g >> 5), c = (int)(g & 31);
            float v = (c < 16) ? lb3[c * H_DIM + row] : 0.f;
            wo[(long)row * KEO + 4096 + c] = f2bf(v);
            return;
        }
        if (bx < 9088) {
            long g = (bx - 8704) * 256 + tid;
            if (g < 6 * 16384) hist[g] = 0u;
        }
        return;
    }
    if (p != 0) return;
    // x cast + lora_a, one row per block
    int m = (int)(bx - 9216);
    const float* xr = x + (long)m * H_DIM;
    int c = tid * 16;
    float4 f0 = *(const float4*)(xr + c);
    float4 f1 = *(const float4*)(xr + c + 4);
    float4 f2 = *(const float4*)(xr + c + 8);
    float4 f3 = *(const float4*)(xr + c + 12);
    *(float4*)(xs + c)      = f0;
    *(float4*)(xs + c + 4)  = f1;
    *(float4*)(xs + c + 8)  = f2;
    *(float4*)(xs + c + 12) = f3;
    ushort8v r0, r1;
    r0[0] = f2bf(f0.x); r0[1] = f2bf(f0.y); r0[2] = f2bf(f0.z); r0[3] = f2bf(f0.w);
    r0[4] = f2bf(f1.x); r0[5] = f2bf(f1.y); r0[6] = f2bf(f1.z); r0[7] = f2bf(f1.w);
    r1[0] = f2bf(f2.x); r1[1] = f2bf(f2.y); r1[2] = f2bf(f2.z); r1[3] = f2bf(f2.w);
    r1[4] = f2bf(f3.x); r1[5] = f2bf(f3.y); r1[6] = f2bf(f3.z); r1[7] = f2bf(f3.w);
    unsigned short* orow = xb_ext + (long)m * KE3 + c;
    *(ushort8v*)orow = r0;
    *(ushort8v*)(orow + 8) = r1;
    __syncthreads();
    int w = tid >> 6, lane = tid & 63;
    if (w < 3) {
        const float* la = (w == 0) ? la0 : (w == 1) ? la1 : la2;
        float s[16];
#pragma unroll
        for (int r = 0; r < 16; ++r) s[r] = 0.f;
        for (int k = lane; k < H_DIM; k += 64) {
            float xv = xs[k];
            const float4* lr = (const float4*)(la + (long)k * RANK);
            float4 q0 = lr[0], q1 = lr[1], q2 = lr[2], q3 = lr[3];
            s[0] += xv * q0.x;  s[1] += xv * q0.y;  s[2] += xv * q0.z;  s[3] += xv * q0.w;
            s[4] += xv * q1.x;  s[5] += xv * q1.y;  s[6] += xv * q1.z;  s[7] += xv * q1.w;
            s[8] += xv * q2.x;  s[9] += xv * q2.y;  s[10] += xv * q2.z; s[11] += xv * q2.w;
            s[12] += xv * q3.x; s[13] += xv * q3.y; s[14] += xv * q3.z; s[15] += xv * q3.w;
        }
        for (int off = 32; off; off >>= 1)
#pragma unroll
            for (int r = 0; r < 16; ++r) s[r] += __shfl_xor(s[r], off);
        if (lane == 0)
#pragma unroll
            for (int r = 0; r < 16; ++r)
                xb_ext[(long)m * KE3 + 4096 + 16 * w + r] = f2bf(s[r]);
    }
}

// xa_o = ob @ la_o (bf16 in) -> bf16 cols of ob_ext
__global__ __launch_bounds__(256) void lora_ao_kernel(
    unsigned short* __restrict__ ob_ext, const float* __restrict__ la) {
    int m = blockIdx.x;
    const unsigned short* xr = ob_ext + (long)m * KEO;
    int tid = threadIdx.x, lane = tid & 63, wid = tid >> 6;
    float s[4] = {0.f, 0.f, 0.f, 0.f};
    for (int k = lane; k < H_DIM; k += 64) {
        float xv = bf2f(xr[k]);
        const float* lr = la + (long)k * RANK + wid * 4;
        s[0] += xv * lr[0]; s[1] += xv * lr[1];
        s[2] += xv * lr[2]; s[3] += xv * lr[3];
    }
    for (int off = 32; off; off >>= 1)
        for (int r = 0; r < 4; ++r) s[r] += __shfl_down(s[r], off);
    if (lane == 0)
        for (int r = 0; r < 4; ++r)
            ob_ext[(long)m * KEO + 4096 + wid * 4 + r] = f2bf(s[r]);
}

// ---------------- bf16 NT GEMM: C[m][n] = alpha*sum_k A[m][k]*B[n][k] (+bias[n]) ------
// Grid: bn = blockIdx.x, bm = blockIdx.y (round-9 order: B partitioned across XCDs).
// mode 0: plain batched (z). mode 1: causal triangular grid (x<36: tri idx, z=head;
//         x in [36,40): v->vT transpose region using tsrc/tdst).
// mode 2: batched + K limited to bm+128 (causal PV). mode 3: split-K2 (z half -> Cv/Cv2).
__global__ __launch_bounds__(256) void gemm_nt(
    const unsigned short* __restrict__ A, const unsigned short* __restrict__ B,
    void* __restrict__ Cv, void* __restrict__ Cv2, const float* __restrict__ bias,
    int K, int lda, int ldb, int ldc,
    long strideA, long strideB, long strideC, float alpha, int mode, int obf,
    const unsigned short* __restrict__ tsrc, unsigned short* __restrict__ tdst) {
    __shared__ unsigned short As[128][32];   // UNPADDED: global_load_lds lane-order
    __shared__ unsigned short Bs[128][32];
    const int tid = threadIdx.x;
    int bm, bn;
    int k0s = 0, k0e = K;
    if (mode == 1) {
        int i = blockIdx.x;
        if (i >= 36) {
            // transpose region: 128 blocks, 32 tiles of 32x32 each, padded LDS
            unsigned short (*tl)[33] = (unsigned short(*)[33])&As[0][0];
            int tb = (i - 36) + 4 * blockIdx.z;
            int tx = tid & 31, ty = tid >> 5;           // 8 rows per pass
            for (int tile = tb; tile < 4096; tile += 128) {
                int tc = tile & 127, ts = tile >> 7;
                int c0 = tc * 32, s0 = ts * 32;
                for (int j = 0; j < 32; j += 8)
                    tl[ty + j][tx] = tsrc[(long)(s0 + ty + j) * H_DIM + c0 + tx];
                __syncthreads();
                for (int j = 0; j < 32; j += 8)
                    tdst[(long)(c0 + ty + j) * S_LEN + s0 + tx] = tl[tx][ty + j];
                __syncthreads();
            }
            return;
        }
        int tm = (int)((sqrtf(8.f * i + 1.f) - 1.f) * 0.5f);
        if ((tm + 1) * (tm + 2) / 2 <= i) tm++;
        if (tm * (tm + 1) / 2 > i) tm--;
        int tn = i - tm * (tm + 1) / 2;
        bm = tm * 128; bn = tn * 128;
    } else {
        bm = blockIdx.y * 128; bn = blockIdx.x * 128;
        if (mode == 2) { int kl = bm + 128; if (kl < k0e) k0e = kl; }
    }
    const unsigned short* Ab = A;
    const unsigned short* Bb = B;
    long coff = 0;
    void* Cuse = Cv;
    if (mode == 3) {
        int Kh = (K / 2) & ~31;
        k0s = blockIdx.z ? Kh : 0;
        k0e = blockIdx.z ? K : Kh;
        Cuse = blockIdx.z ? Cv2 : Cv;
    } else {
        Ab += (long)blockIdx.z * strideA;
        Bb += (long)blockIdx.z * strideB;
        coff = (long)blockIdx.z * strideC;
    }
    const int lane = tid & 63, wid = tid >> 6;
    const int wm = (wid >> 1) * 64, wn = (wid & 1) * 64;
    const int sr = wid * 16 + (lane >> 2);
    const int sc = (lane & 3) * 8;
    const unsigned short* gA0 = Ab + (long)(bm + sr) * lda + sc;
    const unsigned short* gA1 = gA0 + (long)64 * lda;
    const unsigned short* gB0 = Bb + (long)(bn + sr) * ldb + sc;
    const unsigned short* gB1 = gB0 + (long)64 * ldb;
    unsigned short* lA0 = &As[wid * 16][0];
    unsigned short* lA1 = &As[64 + wid * 16][0];
    unsigned short* lB0 = &Bs[wid * 16][0];
    unsigned short* lB1 = &Bs[64 + wid * 16][0];
    f32x4 acc[4][4] = {};
    const int kq = (lane >> 4) * 8;
    const int rr = lane & 15;
    for (int k0 = k0s; k0 < k0e; k0 += 32) {
        GLOAD_LDS16(gA0 + k0, lA0);
        GLOAD_LDS16(gA1 + k0, lA1);
        GLOAD_LDS16(gB0 + k0, lB0);
        GLOAD_LDS16(gB1 + k0, lB1);
        __syncthreads();
        bf16x8 af[4], bfr[4];
        for (int i = 0; i < 4; ++i) {
            uint4 ta = *(const uint4*)&As[wm + i * 16 + rr][kq];
            uint4 tb = *(const uint4*)&Bs[wn + i * 16 + rr][kq];
            af[i]  = __builtin_bit_cast(bf16x8, ta);
            bfr[i] = __builtin_bit_cast(bf16x8, tb);
        }
        for (int i = 0; i < 4; ++i)
            for (int j = 0; j < 4; ++j)
                acc[i][j] = __builtin_amdgcn_mfma_f32_16x16x32_bf16(
                    af[i], bfr[j], acc[i][j], 0, 0, 0);
        __syncthreads();
    }
    const int cr = (lane >> 4) * 4;
    const int cc = lane & 15;
    float bv[4];
#pragma unroll
    for (int j = 0; j < 4; ++j)
        bv[j] = bias ? bias[(long)blockIdx.z * H_DIM + bn + wn + j * 16 + cc] : 0.f;
    if (obf) {
        unsigned short* Cb = (unsigned short*)Cuse + coff;
        for (int i = 0; i < 4; ++i)
            for (int j = 0; j < 4; ++j) {
                unsigned short* cp = Cb + (long)(bm + wm + i * 16 + cr) * ldc
                                        + (bn + wn + j * 16 + cc);
                for (int r = 0; r < 4; ++r)
                    cp[(long)r * ldc] = f2bf(acc[i][j][r] * alpha + bv[j]);
            }
    } else {
        float* Cb = (float*)Cuse + coff;
        for (int i = 0; i < 4; ++i)
            for (int j = 0; j < 4; ++j) {
                float* cp = Cb + (long)(bm + wm + i * 16 + cr) * ldc
                               + (bn + wn + j * 16 + cc);
                for (int r = 0; r < 4; ++r)
                    cp[(long)r * ldc] = acc[i][j][r] * alpha + bv[j];
            }
    }
}

// ---------------- causal softmax, bf16 in/out in-place, 2 balanced rows/block ----
__global__ __launch_bounds__(256) void softmax_causal(unsigned short* __restrict__ scores16) {
    int b = blockIdx.x;
    int h = b >> 9, pr = b & 511;
    int tid = threadIdx.x, lane = tid & 63, wid = tid >> 6;
    __shared__ float red[4], red2[4];
    for (int half = 0; half < 2; ++half) {
        int i = half ? (S_LEN - 1 - pr) : pr;
        unsigned short* row = scores16 + ((long)h * S_LEN + i) * S_LEN;
        int L = i + 1;
        float v[4];
        float mx = -1e30f;
        for (int t = 0; t < 4; ++t) {
            int j = tid + (t << 8);
            v[t] = (j < L) ? bf2f(row[j]) : -1e30f;
            mx = fmaxf(mx, v[t]);
        }
        for (int off = 32; off; off >>= 1) mx = fmaxf(mx, __shfl_xor(mx, off));
        if (lane == 0) red[wid] = mx;
        __syncthreads();
        mx = fmaxf(fmaxf(red[0], red[1]), fmaxf(red[2], red[3]));
        float e[4], sum = 0.f;
        for (int t = 0; t < 4; ++t) {
            int j = tid + (t << 8);
            e[t] = (j < L) ? __expf(v[t] - mx) : 0.f;
            sum += e[t];
        }
        for (int off = 32; off; off >>= 1) sum += __shfl_xor(sum, off);
        if (lane == 0) red2[wid] = sum;
        __syncthreads();
        sum = red2[0] + red2[1] + red2[2] + red2[3];
        float inv = 1.f / sum;
        for (int t = 0; t < 4; ++t) {
            int j = tid + (t << 8);
            row[j] = f2bf(e[t] * inv);
        }
        __syncthreads();
    }
}

// ---------------- mega histogram: 6 tensors, flat weighted grid (1536 blocks) ----
// [0,256) x fp32 | [256,384) q | [384,512) k | [512,640) v | [640,768) o | [768,1536) P
__global__ __launch_bounds__(256, 2) void hist6(
    const float* __restrict__ x, const unsigned short* __restrict__ qkv,
    const unsigned short* __restrict__ ob, const unsigned short* __restrict__ P,
    unsigned int* __restrict__ hist) {
    __shared__ unsigned int lh[16384];
    const long SH = (long)S_LEN * H_DIM;
    int t = threadIdx.x;
    int b = blockIdx.x;
    int ten, b0, nblk;
    if (b < 256)      { ten = 0; b0 = 0;   nblk = 256; }
    else if (b < 384) { ten = 1; b0 = 256; nblk = 128; }
    else if (b < 512) { ten = 2; b0 = 384; nblk = 128; }
    else if (b < 640) { ten = 3; b0 = 512; nblk = 128; }
    else if (b < 768) { ten = 4; b0 = 640; nblk = 128; }
    else              { ten = 5; b0 = 768; nblk = 768; }
    unsigned int* gh = hist + (long)ten * 16384;
    for (int k = t; k < 16384; k += 256) lh[k] = 0u;
    __syncthreads();
    long i = (long)(b - b0) * 256 + t;
    long stride = (long)nblk * 256;
    if (ten == 0) {
        for (; i < SH / 4; i += stride) {
            float4 v = *(const float4*)(x + i * 4);
            unsigned int u0 = (__builtin_bit_cast(unsigned int, v.x) & 0x7FFFFFFFu) >> 16;
            unsigned int u1 = (__builtin_bit_cast(unsigned int, v.y) & 0x7FFFFFFFu) >> 16;
            unsigned int u2 = (__builtin_bit_cast(unsigned int, v.z) & 0x7FFFFFFFu) >> 16;
            unsigned int u3 = (__builtin_bit_cast(unsigned int, v.w) & 0x7FFFFFFFu) >> 16;
            atomicAdd(&lh[u0 < 16384u ? u0 : 16383u], 1u);
            atomicAdd(&lh[u1 < 16384u ? u1 : 16383u], 1u);
            atomicAdd(&lh[u2 < 16384u ? u2 : 16383u], 1u);
            atomicAdd(&lh[u3 < 16384u ? u3 : 16383u], 1u);
        }
    } else if (ten <= 3) {
        const unsigned short* src = qkv + (size_t)(ten - 1) * SH;
        for (; i < SH / 8; i += stride) {
            ushort8v v = ((const ushort8v*)src)[i];
#pragma unroll
            for (int j = 0; j < 8; ++j) {
                unsigned int u = v[j] & 0x7FFFu;
                atomicAdd(&lh[u < 16384u ? u : 16383u], 1u);
            }
        }
    } else if (ten == 4) {
        for (; i < SH / 8; i += stride) {
            long off = (i >> 9) * KEO + ((i & 511) << 3);
            ushort8v v = *(const ushort8v*)(ob + off);
#pragma unroll
            for (int j = 0; j < 8; ++j) {
                unsigned int u = v[j] & 0x7FFFu;
                atomicAdd(&lh[u < 16384u ? u : 16383u], 1u);
            }
        }
    } else {
        unsigned int zc = 0;
        for (; i < TOTP / 8; i += stride) {
            ushort8v v = ((const ushort8v*)P)[i];
#pragma unroll
            for (int j = 0; j < 8; ++j) {
                unsigned int bb = v[j];
                if (bb == 0) zc++;
                else atomicAdd(&lh[bb < 16384u ? bb : 16383u], 1u);
            }
        }
        if (zc) atomicAdd(&lh[0], zc);
    }
    __syncthreads();
    for (int k = t; k < 16384; k += 256) {
        unsigned int c = lh[k];
        if (c) atomicAdd(&gh[k], c);
    }
}

// ---------------- finish: combine split-K + bias (b<4096) | scan6 (b>=4096) ------
__global__ __launch_bounds__(256) void finish_kernel(
    float* __restrict__ out, const float* __restrict__ part,
    const float* __restrict__ bias, const unsigned int* __restrict__ hist,
    float* __restrict__ out_kth) {
    int b = blockIdx.x;
    int t = threadIdx.x;
    if (b < 4096) {
        long idx = ((long)b * 256 + t) * 4;
        int n = (int)(idx & 4095);
        float4 o = *(float4*)(out + idx);
        float4 p = *(const float4*)(part + idx);
        float4 bb = *(const float4*)(bias + n);
        o.x += p.x + bb.x; o.y += p.y + bb.y; o.z += p.z + bb.z; o.w += p.w + bb.w;
        *(float4*)(out + idx) = o;
        return;
    }
    int ten = b - 4096;
    const unsigned int* h = hist + (long)ten * 16384;
    __shared__ unsigned int partl[256];
    unsigned int s = 0;
    for (int bb = 0; bb < 64; ++bb) s += h[t * 64 + bb];
    partl[t] = s;
    __syncthreads();
    if (t == 0) {
        long k = (ten == 5) ? TOTP / 2 : (long)S_LEN * H_DIM / 2;
        long c = 0;
        int ch = 0;
        for (; ch < 256; ++ch) {
            if (c + (long)partl[ch] >= k) break;
            c += partl[ch];
        }
        int bin = ch * 64;
        for (;; ++bin) {
            unsigned int hv = h[bin];
            if (c + (long)hv >= k) break;
            c += hv;
        }
        int slot = (ten == 4) ? 5 : (ten == 5) ? 4 : ten;
        out_kth[slot] = __builtin_bit_cast(float, (unsigned int)bin << 16);
    }
}

// ==================================================================
extern "C" void kernel_launch(void* const* d_in, const int* in_sizes, int n_in,
                              void* d_out, int out_size, void* d_ws, size_t ws_size,
                              hipStream_t stream) {
    (void)in_sizes; (void)n_in; (void)out_size; (void)ws_size;
    const float* x = (const float*)d_in[0];
    const int*   wcodes[4] = {(const int*)d_in[1], (const int*)d_in[6],
                              (const int*)d_in[11], (const int*)d_in[16]};
    const float* wabs[4]   = {(const float*)d_in[2], (const float*)d_in[7],
                              (const float*)d_in[12], (const float*)d_in[17]};
    const float* bias[4]   = {(const float*)d_in[3], (const float*)d_in[8],
                              (const float*)d_in[13], (const float*)d_in[18]};
    const float* lA[4]     = {(const float*)d_in[4], (const float*)d_in[9],
                              (const float*)d_in[14], (const float*)d_in[19]};
    const float* lB[4]     = {(const float*)d_in[5], (const float*)d_in[10],
                              (const float*)d_in[15], (const float*)d_in[20]};

    char* wp = (char*)d_ws;
    auto alloc = [&](size_t bytes) {
        char* p = wp; wp += (bytes + 255) & ~(size_t)255; return p;
    };
    const size_t SH  = (size_t)S_LEN * H_DIM;       // 4,194,304
    const long   nW  = (long)H_DIM * H_DIM;
    unsigned short* xb_ext = (unsigned short*)alloc((size_t)S_LEN * KE3 * 2);
    unsigned short* qkvb   = (unsigned short*)alloc(3 * SH * 2);  // q,k,v bf16
    unsigned short* vT     = (unsigned short*)alloc(SH * 2);
    unsigned short* ob_ext = (unsigned short*)alloc((size_t)S_LEN * KEO * 2);
    unsigned short* Wd_ext = (unsigned short*)alloc((size_t)H_DIM * KEO * 2);
    float*        opart  = (float*)alloc(SH * 4);
    float*        bias3  = (float*)alloc(3 * H_DIM * 4);
    unsigned int* hist   = (unsigned int*)alloc(6 * 16384 * 4);
    // scores16 (bf16 P, 67 MB) aliases the region that first holds Wqkv_ext (102 MB)
    char* bigbuf = alloc((size_t)3 * H_DIM * KE3 * 2);
    unsigned short* Wqkv_ext = (unsigned short*)bigbuf;
    unsigned short* scores16 = (unsigned short*)bigbuf;

    float* out_final = (float*)d_out;
    float* out_kth   = out_final + SH;

    unsigned short* qb = qkvb;
    unsigned short* kb = qkvb + SH;
    unsigned short* vb = qkvb + 2 * SH;

    // 1) prep: dequants + pads + bias + hist zero + x cast/lora (early region)
    prep_weights<<<dim3(10240, 4), 256, 0, stream>>>(
        wcodes[0], wcodes[1], wcodes[2], wcodes[3],
        wabs[0], wabs[1], wabs[2], wabs[3],
        lB[0], lB[1], lB[2], lB[3],
        bias[0], bias[1], bias[2],
        x, lA[0], lA[1], lA[2],
        Wqkv_ext, Wd_ext, bias3, xb_ext, hist, nW);

    // 2) QKV: ONE z=3 batched GEMM over K=4160 (round-9 grid order)
    gemm_nt<<<dim3(32, 8, 3), 256, 0, stream>>>(
        xb_ext, Wqkv_ext, qkvb, nullptr, bias3, KE3, KE3, KE3, H_DIM,
        0, (long)H_DIM * KE3, (long)SH, 1.0f, 0, 1, nullptr, nullptr);

    // 3) scores16 = q.kT / sqrt(128) bf16 (36 tri tiles/head) + v->vT (x>=36 region)
    gemm_nt<<<dim3(40, 1, NHEAD), 256, 0, stream>>>(
        qb, kb, scores16, nullptr, nullptr, HEAD_D, H_DIM, H_DIM, S_LEN,
        128, 128, (long)S_LEN * S_LEN, 0.08838834764831845f, 1, 1, vb, vT);

    // 4) softmax in-place bf16, 2 balanced rows per block
    softmax_causal<<<NHEAD * S_LEN / 2, 256, 0, stream>>>(scores16);

    // 5) o = P.v -> ob_ext (bf16, row stride KEO); mode 2 limits K to bm+128
    gemm_nt<<<dim3(1, 8, NHEAD), 256, 0, stream>>>(
        scores16, vT, ob_ext, nullptr, nullptr, S_LEN,
        S_LEN, S_LEN, KEO,
        (long)S_LEN * S_LEN, (long)HEAD_D * S_LEN, 128, 1.0f, 2, 1, nullptr, nullptr);

    // 6) xa_o columns
    lora_ao_kernel<<<S_LEN, 256, 0, stream>>>(ob_ext, lA[3]);

    // 7) O projection: split-K2 (z=2), round-9 grid order
    gemm_nt<<<dim3(32, 8, 2), 256, 0, stream>>>(
        ob_ext, Wd_ext, out_final, opart, nullptr, KEO, KEO, KEO, H_DIM,
        0, 0, 0, 1.0f, 3, 0, nullptr, nullptr);

    // 8) k-th selects: one 6-tensor histogram (hist zeroed in prep)
    hist6<<<1536, 256, 0, stream>>>(x, qkvb, ob_ext, scores16, hist);

    // 9) finish: combine split-K partials + bias, and scan the 6 histograms
    finish_kernel<<<4102, 256, 0, stream>>>(out_final, opart, bias[3], hist, out_kth);
}